// Round 3
// baseline (122.850 us; speedup 1.0000x reference)
//
#include <hip/hip_runtime.h>

// RBCombiner: out[token] = sum of weighted dout_exp rows routed via indices.
// TOP_K = 2 (reference module constant) -> token = idx >> 1.
#define TOPK_SHIFT 1

__device__ inline void fma4(float4& a, float w, const float4& v) {
    a.x = fmaf(w, v.x, a.x);
    a.y = fmaf(w, v.y, a.y);
    a.z = fmaf(w, v.z, a.z);
    a.w = fmaf(w, v.w, a.w);
}

// ---------------------------------------------------------------------------
// K1: build (token, weight) per entry + histogram of tokens.
// Entry i < S1: s1 row i, token = indices_s1[i]>>1, w = weights[indices_s1[i]]
// Entry i >= S1 (j = i-S1): s2 row (dout row i), routed through its target s1
//   row: token = indices_s1[s1exp_to_s2[j]]>>1, w = weights[indices_s2[j]]
// src row in dout_exp is exactly i in both cases.
// ---------------------------------------------------------------------------
__global__ void build_entries_kernel(
    const int* __restrict__ indices_s1,
    const int* __restrict__ indices_s2,
    const int* __restrict__ s1_to_s2,
    const float* __restrict__ weights,
    int S1, int S2,
    int* __restrict__ counts,
    int* __restrict__ etoken,
    float* __restrict__ ew)
{
    int i = blockIdx.x * blockDim.x + threadIdx.x;
    int n = S1 + S2;
    if (i >= n) return;
    int token;
    float w;
    if (i < S1) {
        int idx = indices_s1[i];
        token = idx >> TOPK_SHIFT;
        w = weights[idx];
    } else {
        int j = i - S1;
        int tgt = s1_to_s2[j];
        token = indices_s1[tgt] >> TOPK_SHIFT;
        w = weights[indices_s2[j]];
    }
    etoken[i] = token;
    ew[i] = w;
    atomicAdd(&counts[token], 1);
}

// ---------------------------------------------------------------------------
// K2: single-block exclusive scan over counts[n] -> offsets[n+1].
// n <= 32768 (per-thread chunk <= 32). n = 8192 here (per = 8).
// ---------------------------------------------------------------------------
__global__ __launch_bounds__(1024) void scan_kernel(
    const int* __restrict__ counts, int* __restrict__ offsets, int n)
{
    __shared__ int lds[1024];
    const int t = threadIdx.x;
    const int per = (n + 1023) / 1024;
    int local[32];
    int base = t * per;
    int sum = 0;
    for (int k = 0; k < per; ++k) {
        int idx = base + k;
        int c = (idx < n) ? counts[idx] : 0;
        local[k] = sum;   // exclusive prefix within this thread's chunk
        sum += c;
    }
    lds[t] = sum;
    __syncthreads();
    // Hillis-Steele inclusive scan over the 1024 partial sums.
    for (int off = 1; off < 1024; off <<= 1) {
        int v = (t >= off) ? lds[t - off] : 0;
        __syncthreads();
        lds[t] += v;
        __syncthreads();
    }
    int block_excl = (t == 0) ? 0 : lds[t - 1];
    for (int k = 0; k < per; ++k) {
        int idx = base + k;
        if (idx < n) offsets[idx] = block_excl + local[k];
    }
    if (t == 1023) offsets[n] = lds[1023];
}

// ---------------------------------------------------------------------------
// K3: scatter entries into CSR slots (order within a bucket is arbitrary; fp
// summation order differences are rounding-level only).
// ---------------------------------------------------------------------------
__global__ void scatter_kernel(
    const int* __restrict__ etoken,
    const float* __restrict__ ew,
    const int* __restrict__ offsets,
    int* __restrict__ cursors,
    int* __restrict__ csr_src,
    float* __restrict__ csr_w,
    int n)
{
    int i = blockIdx.x * blockDim.x + threadIdx.x;
    if (i >= n) return;
    int t = etoken[i];
    int pos = offsets[t] + atomicAdd(&cursors[t], 1);
    csr_src[pos] = i;           // src row in dout_exp == entry index
    csr_w[pos]  = ew[i];
}

// ---------------------------------------------------------------------------
// K4: the fat kernel. One block (256 threads) per output token. Each thread
// owns 4 float4 lanes (stride-256 interleave -> 16 B/lane fully coalesced).
// Accumulate all contributing rows in registers, write out once.
// ---------------------------------------------------------------------------
__global__ __launch_bounds__(256) void gather_kernel(
    const float4* __restrict__ dout,     // (S1+S2) x D4
    const int*    __restrict__ offsets,  // NT+1
    const int*    __restrict__ csr_src,
    const float*  __restrict__ csr_w,
    float4*       __restrict__ out,      // NT x D4
    int D4)
{
    const int t   = blockIdx.x;
    const int beg = offsets[t];
    const int end = offsets[t + 1];
    const int tid = threadIdx.x;

    if ((D4 & 1023) == 0) {
        // fast path: D4 multiple of 1024 (D=4096 -> one pass)
        for (int base = 0; base < D4; base += 1024) {
            float4 a0 = make_float4(0.f, 0.f, 0.f, 0.f);
            float4 a1 = a0, a2 = a0, a3 = a0;
            for (int e = beg; e < end; ++e) {
                const float w = csr_w[e];
                const float4* row = dout + (size_t)csr_src[e] * (size_t)D4 + base;
                float4 v0 = row[tid];
                float4 v1 = row[tid + 256];
                float4 v2 = row[tid + 512];
                float4 v3 = row[tid + 768];
                fma4(a0, w, v0);
                fma4(a1, w, v1);
                fma4(a2, w, v2);
                fma4(a3, w, v3);
            }
            float4* orow = out + (size_t)t * (size_t)D4 + base;
            orow[tid]       = a0;
            orow[tid + 256] = a1;
            orow[tid + 512] = a2;
            orow[tid + 768] = a3;
        }
    } else {
        // generic fallback (not hit for D=4096)
        for (int c = tid; c < D4; c += 256) {
            float4 acc = make_float4(0.f, 0.f, 0.f, 0.f);
            for (int e = beg; e < end; ++e) {
                const float w = csr_w[e];
                float4 v = dout[(size_t)csr_src[e] * (size_t)D4 + c];
                fma4(acc, w, v);
            }
            out[(size_t)t * (size_t)D4 + c] = acc;
        }
    }
}

// ---------------------------------------------------------------------------
// Launch. Inputs (setup_inputs order):
//   0: dout_exp  (S1+S2, D) f32
//   1: weights   (S1,)      f32
//   2: indices_s1 (S1,)     i32
//   3: indices_s2 (S2,)     i32
//   4: s1exp_to_s2_indices (S2,) i32
//   5: n_tokens (scalar, device) -- derived instead as out_size / D
// ---------------------------------------------------------------------------
extern "C" void kernel_launch(void* const* d_in, const int* in_sizes, int n_in,
                              void* d_out, int out_size, void* d_ws, size_t ws_size,
                              hipStream_t stream) {
    const float* dout_exp   = (const float*)d_in[0];
    const float* weights    = (const float*)d_in[1];
    const int*   indices_s1 = (const int*)d_in[2];
    const int*   indices_s2 = (const int*)d_in[3];
    const int*   s1_to_s2   = (const int*)d_in[4];

    const int S1    = in_sizes[1];          // weights length == S1_ROWS
    const int S2    = in_sizes[3];          // indices_s2 length == S2_ROWS
    const int NROWS = S1 + S2;
    const int D     = in_sizes[0] / NROWS;  // 4096
    const int NT    = out_size / D;         // n_tokens = 8192
    const int D4    = D / 4;
    const int NE    = NROWS;                // 20480 entries

    // Workspace layout (all int/float, 4B-aligned): ~508 KB total.
    int*   counts  = (int*)d_ws;            // NT
    int*   cursors = counts + NT;           // NT
    int*   offsets = cursors + NT;          // NT+1
    int*   etoken  = offsets + NT + 1;      // NE
    float* ew      = (float*)(etoken + NE); // NE
    int*   csr_src = (int*)(ew + NE);       // NE
    float* csr_w   = (float*)(csr_src + NE);// NE

    // Re-zero histogram + cursors every call (graph-replay safe).
    hipMemsetAsync(counts, 0, (size_t)2 * NT * sizeof(int), stream);

    const int threads = 256;
    const int eblocks = (NE + threads - 1) / threads;

    build_entries_kernel<<<eblocks, threads, 0, stream>>>(
        indices_s1, indices_s2, s1_to_s2, weights, S1, S2,
        counts, etoken, ew);

    scan_kernel<<<1, 1024, 0, stream>>>(counts, offsets, NT);

    scatter_kernel<<<eblocks, threads, 0, stream>>>(
        etoken, ew, offsets, cursors, csr_src, csr_w, NE);

    gather_kernel<<<NT, 256, 0, stream>>>(
        (const float4*)dout_exp, offsets, csr_src, csr_w,
        (float4*)d_out, D4);
}